// Round 4
// baseline (320.483 us; speedup 1.0000x reference)
//
#include <hip/hip_runtime.h>

// LocalLayer, split-o two-block-per-CU version.
// kernel1 (512 blocks = 2 per unit): partial pred (f32) + partial softmax-denoms -> ws
//   m1: a = (p_hi + p_lo) · W_hi^T   (bf16 MFMA, 2 passes; x·w_lo term dropped ~3e-4)
//   e = exp(beta*a) (shift-free softmax), m2: pred_part = e · W_hi
// kernel2: out = (P0+P1) / (l0+l1), scattered to image layout.

#define OUTC 1000
#define Pp 192
#define Bb 64
#define OT 32
#define NT 16
#define THREADS 512
#define BETA 10.0f

typedef __attribute__((ext_vector_type(8))) short short8;
typedef __attribute__((ext_vector_type(4))) float f32x4;

#define MFMA(a, b, c) __builtin_amdgcn_mfma_f32_16x16x32_bf16((a), (b), (c), 0, 0, 0)

__device__ __forceinline__ unsigned f2bf(float f) {  // RNE f32->bf16 bits
  unsigned u = __float_as_uint(f);
  return (u + 0x7fffu + ((u >> 16) & 1u)) >> 16;
}

// byte addrs. pH/pL, wH: XOR-swizzled 16B blocks (frag reads ~2-way).
__device__ __forceinline__ int paddr(int b, int p) {   // [64][192] bf16
  return b * 384 + ((((p) >> 3) ^ (b & 7)) << 4) + ((p) & 7) * 2;
}
__device__ __forceinline__ int waddr(int o, int p) {   // [32][192] bf16
  int f = (o & 7) ^ ((o >> 3) & 3);
  return o * 384 + ((((p) >> 3) ^ f) << 4) + ((p) & 7) * 2;
}
__device__ __forceinline__ int eaddr(int b, int o) {   // [64] rows, 80B stride
  return b * 80 + o * 2;
}

__global__ __launch_bounds__(THREADS, 4)
void ll_main(const float* __restrict__ x, const float* __restrict__ W,
             float* __restrict__ predWs, float* __restrict__ lWs) {
  __shared__ unsigned short pH[Bb * Pp];       // 24 KB
  __shared__ unsigned short pL[Bb * Pp];       // 24 KB
  __shared__ unsigned short wHb[2][OT * Pp];   // 24 KB (double-buffered W-hi)
  __shared__ unsigned short eSs[Bb * 40];      // 5 KB (80B row stride)
  char* pHc = (char*)pH; char* pLc = (char*)pL; char* eSc = (char*)eSs;

  const int bid = blockIdx.x;
  const int u = bid >> 1, q = bid & 1;
  const int uw = u >> 4, uh = u & 15;
  const int obase = q * 512;
  const int tid = threadIdx.x, wv = tid >> 6, lane = tid & 63;
  const int lr = lane & 15, lg = lane >> 4;
  const int mq = wv & 3, ov = wv >> 2;   // m1 roles: b-frag 16*mq, o-frag 16*ov
  const int mw = wv & 1, ow = wv >> 1;   // m2 roles: b-half 32*mw, p-range 48*ow

  const float* Wu = W + (size_t)u * (OUTC * Pp);

  // ---- stage patches -> pH/pL (hi/lo bf16) ----
#pragma unroll
  for (int k = 0; k < 6; ++k) {
    int i4 = tid + THREADS * k;
    int b = i4 / 48, p = (i4 % 48) * 4;
    int c = p >> 6, kh = (p >> 3) & 7, kw = p & 7;
    float4 v = *reinterpret_cast<const float4*>(
        x + ((size_t)((b * 3 + c) * 128 + uw * 8 + kh) * 128 + uh * 8 + kw));
    unsigned h0 = f2bf(v.x), h1 = f2bf(v.y), h2 = f2bf(v.z), h3 = f2bf(v.w);
    float l0 = v.x - __uint_as_float(h0 << 16);
    float l1 = v.y - __uint_as_float(h1 << 16);
    float l2 = v.z - __uint_as_float(h2 << 16);
    float l3 = v.w - __uint_as_float(h3 << 16);
    unsigned g0 = f2bf(l0), g1 = f2bf(l1), g2 = f2bf(l2), g3 = f2bf(l3);
    *reinterpret_cast<uint2*>(pHc + paddr(b, p)) = make_uint2(h0 | (h1 << 16), h2 | (h3 << 16));
    *reinterpret_cast<uint2*>(pLc + paddr(b, p)) = make_uint2(g0 | (g1 << 16), g2 | (g3 << 16));
  }

  // ---- W tile 0: load + convert (hi only) ----
  float4 R[3];
#pragma unroll
  for (int k = 0; k < 3; ++k) {
    int i4 = tid + THREADS * k;
    int o = i4 / 48, p = (i4 % 48) * 4;
    int og = obase + o; og = og < OUTC ? og : OUTC - 1;
    R[k] = *reinterpret_cast<const float4*>(Wu + (size_t)og * Pp + p);
  }
#pragma unroll
  for (int k = 0; k < 3; ++k) {
    int i4 = tid + THREADS * k;
    int o = i4 / 48, p = (i4 % 48) * 4;
    unsigned h0 = f2bf(R[k].x), h1 = f2bf(R[k].y), h2 = f2bf(R[k].z), h3 = f2bf(R[k].w);
    *reinterpret_cast<uint2*>((char*)wHb[0] + waddr(o, p)) =
        make_uint2(h0 | (h1 << 16), h2 | (h3 << 16));
  }
  __syncthreads();

  // ---- hoist patch-hi A-frags (rows 16*mq + lr); patch-lo read per use ----
  short8 pa_h[6];
#pragma unroll
  for (int ks = 0; ks < 6; ++ks)
    pa_h[ks] = *reinterpret_cast<const short8*>(pHc + paddr(16 * mq + lr, 32 * ks + 8 * lg));

  f32x4 pacc[2][3];
#pragma unroll
  for (int h = 0; h < 2; ++h)
#pragma unroll
    for (int f = 0; f < 3; ++f) pacc[h][f] = (f32x4){0.f, 0.f, 0.f, 0.f};
  float lPart[4] = {0.f, 0.f, 0.f, 0.f};

  for (int t = 0; t < NT; ++t) {
    char* wc = (char*)wHb[t & 1];

    // ---- issue loads for tile t+1 ----
    if (t + 1 < NT) {
#pragma unroll
      for (int k = 0; k < 3; ++k) {
        int i4 = tid + THREADS * k;
        int o = i4 / 48, p = (i4 % 48) * 4;
        int og = obase + (t + 1) * OT + o; og = og < OUTC ? og : OUTC - 1;
        R[k] = *reinterpret_cast<const float4*>(Wu + (size_t)og * Pp + p);
      }
    }

    // ---- m1: a[16 mq-rows][16 ov-cols], 2 passes (p_hi + p_lo) x W_hi ----
    f32x4 aH = (f32x4){0.f, 0.f, 0.f, 0.f};
    f32x4 aL = (f32x4){0.f, 0.f, 0.f, 0.f};
#pragma unroll
    for (int ks = 0; ks < 6; ++ks) {
      const int ko = 32 * ks + 8 * lg;
      short8 wb = *reinterpret_cast<const short8*>(wc + waddr(16 * ov + lr, ko));
      short8 pl = *reinterpret_cast<const short8*>(pLc + paddr(16 * mq + lr, ko));
      aH = MFMA(pa_h[ks], wb, aH);
      aL = MFMA(pl, wb, aL);
    }

    // ---- e = exp(beta*a), zero invalid o, write eS ----
    {
      const int o_l = 16 * ov + lr;
      const bool valid = (obase + t * OT + o_l) < OUTC;
#pragma unroll
      for (int j = 0; j < 4; ++j) {
        float e = valid ? __expf(BETA * (aH[j] + aL[j])) : 0.f;
        lPart[j] += e;
        *reinterpret_cast<unsigned short*>(
            eSc + eaddr(16 * mq + 4 * lg + j, o_l)) = (unsigned short)f2bf(e);
      }
    }
    __syncthreads();   // BAR1: eS complete

    // ---- m2: pred[32*mw rows][48*ow p-cols] += e · W_hi (k = 32) ----
    short8 ea0 = *reinterpret_cast<const short8*>(eSc + eaddr(32 * mw + lr, 8 * lg));
    short8 ea1 = *reinterpret_cast<const short8*>(eSc + eaddr(32 * mw + 16 + lr, 8 * lg));
#pragma unroll
    for (int f = 0; f < 3; ++f) {
      const int p = 48 * ow + 16 * f + lr;
      short8 wb;
#pragma unroll
      for (int e8 = 0; e8 < 8; ++e8)
        wb[e8] = *reinterpret_cast<const short*>(wc + waddr(8 * lg + e8, p));
      pacc[0][f] = MFMA(ea0, wb, pacc[0][f]);
      pacc[1][f] = MFMA(ea1, wb, pacc[1][f]);
    }

    // ---- convert+write tile t+1 into other buffer ----
    if (t + 1 < NT) {
      char* nc = (char*)wHb[(t + 1) & 1];
#pragma unroll
      for (int k = 0; k < 3; ++k) {
        int i4 = tid + THREADS * k;
        int o = i4 / 48, p = (i4 % 48) * 4;
        unsigned h0 = f2bf(R[k].x), h1 = f2bf(R[k].y), h2 = f2bf(R[k].z), h3 = f2bf(R[k].w);
        *reinterpret_cast<uint2*>(nc + waddr(o, p)) =
            make_uint2(h0 | (h1 << 16), h2 | (h3 << 16));
      }
    }
    __syncthreads();   // BAR2: next tile visible; eS free
  }

  // ---- partial denominators: reduce lPart over 16 lr lanes, store to ws ----
#pragma unroll
  for (int j = 0; j < 4; ++j) {
    float v = lPart[j];
    v += __shfl_xor(v, 1, 16);
    v += __shfl_xor(v, 2, 16);
    v += __shfl_xor(v, 4, 16);
    v += __shfl_xor(v, 8, 16);
    if (lr == 0)
      lWs[(u * 2 + q) * 128 + ov * 64 + 16 * mq + 4 * lg + j] = v;
  }

  // ---- partial pred -> ws [u*2+q][b][p] f32 ----
  float* P = predWs + (size_t)(u * 2 + q) * (Bb * Pp);
#pragma unroll
  for (int h = 0; h < 2; ++h)
#pragma unroll
    for (int f = 0; f < 3; ++f) {
      const int p = 48 * ow + 16 * f + lr;
#pragma unroll
      for (int j = 0; j < 4; ++j)
        P[(32 * mw + 16 * h + 4 * lg + j) * Pp + p] = pacc[h][f][j];
    }
}

__global__ __launch_bounds__(256)
void ll_fin(const float* __restrict__ predWs, const float* __restrict__ lWs,
            float* __restrict__ out) {
  int t4 = blockIdx.x * 256 + threadIdx.x;   // 786432 threads, 4 outputs each
  int f = t4 * 4;
  int Y = f & 127, X = (f >> 7) & 127, r = f >> 14;
  int c = r % 3, b = r / 3;
  int uw = X >> 3, kh = X & 7, uh = Y >> 3, kw = Y & 7;
  int u = uw * 16 + uh, p = c * 64 + kh * 8 + kw;
  float4 s0 = *reinterpret_cast<const float4*>(predWs + (size_t)(2 * u) * (Bb * Pp) + b * Pp + p);
  float4 s1 = *reinterpret_cast<const float4*>(predWs + (size_t)(2 * u + 1) * (Bb * Pp) + b * Pp + p);
  float l = lWs[(2 * u) * 128 + b] + lWs[(2 * u) * 128 + 64 + b] +
            lWs[(2 * u + 1) * 128 + b] + lWs[(2 * u + 1) * 128 + 64 + b];
  float inv = 1.f / l;
  float4 o4 = make_float4((s0.x + s1.x) * inv, (s0.y + s1.y) * inv,
                          (s0.z + s1.z) * inv, (s0.w + s1.w) * inv);
  *reinterpret_cast<float4*>(out + f) = o4;
}

extern "C" void kernel_launch(void* const* d_in, const int* in_sizes, int n_in,
                              void* d_out, int out_size, void* d_ws, size_t ws_size,
                              hipStream_t stream) {
  const float* x = (const float*)d_in[0];
  const float* W = (const float*)d_in[1];
  float* out = (float*)d_out;
  float* predWs = (float*)d_ws;                       // 512 * 64*192 f32 = 25.2 MB
  float* lWs = predWs + (size_t)512 * (Bb * Pp);      // 512 * 128 f32
  hipLaunchKernelGGL(ll_main, dim3(512), dim3(THREADS), 0, stream, x, W, predWs, lWs);
  hipLaunchKernelGGL(ll_fin, dim3(3072), dim3(256), 0, stream, predWs, lWs, out);
}